// Round 6
// baseline (134.429 us; speedup 1.0000x reference)
//
#include <hip/hip_runtime.h>
#include <math.h>

// Problem dims
#define S_   8
#define B_   16
#define D_   10
#define N_   32
#define E_   300
#define H_   128
#define G4_  512
#define SDIM_ 96
#define MID_ 256
#define TOT_ 528

#define NWPACK 3850240   // 8*47*320*32  (wpack2)
#define NWPRE  1310720   // 8*10*512*32  (wpre2)

typedef unsigned short u16;
typedef __attribute__((ext_vector_type(8))) short short8;
typedef __attribute__((ext_vector_type(4))) short short4v;
typedef __attribute__((ext_vector_type(4))) float f32x4;

// round-to-nearest-even f32 -> bf16
static __device__ __forceinline__ u16 f2bf(float f) {
    unsigned u = __builtin_bit_cast(unsigned, f);
    return (u16)((u + 0x7FFFu + ((u >> 16) & 1u)) >> 16);
}

// ---------------------------------------------------------------------------
// prep: wpack2[s][ks=47][c=320][q=4][j=8] bf16 (K-step-major, coalesced);
//       wpre2[s][ks=10][g=512][q=4][j=8] bf16; bcomb[s][320] f32;
//       lxwT[s][256][128], lywT[s][128][64], aw1T[528][256] f32 transposes.
// ---------------------------------------------------------------------------
__global__ void prep(const float* __restrict__ w3, const float* __restrict__ b3,
                     const float* __restrict__ w4, const float* __restrict__ b4,
                     const float* __restrict__ w5, const float* __restrict__ b5,
                     const float* __restrict__ w_ih,
                     const float* __restrict__ lxw, const float* __restrict__ lyw,
                     const float* __restrict__ aw1,
                     u16* __restrict__ wpack2, u16* __restrict__ wpre2,
                     float* __restrict__ bcomb,
                     float* __restrict__ lxwT, float* __restrict__ lywT,
                     float* __restrict__ aw1T) {
    int idx = blockIdx.x * blockDim.x + threadIdx.x;
    if (idx < NWPACK) {
        int j = idx & 7, q = (idx >> 3) & 3;
        int rest = idx >> 5;
        int c = rest % 320, ks = (rest / 320) % 47, s = rest / 15040;
        int kk = ks * 32 + q * 8 + j;
        int tap = kk / 300, e = kk - tap * 300;
        float v = 0.f;
        if (tap < 5) {
            if (c < 100)      { if (tap < 3) v = w3[((s*100 + c      )*300 + e)*3 + tap]; }
            else if (c < 200) { if (tap < 4) v = w4[((s*100 + c - 100)*300 + e)*4 + tap]; }
            else if (c < 300) {              v = w5[((s*100 + c - 200)*300 + e)*5 + tap]; }
        }
        wpack2[idx] = f2bf(v);
    } else if (idx < NWPACK + NWPRE) {
        int i2 = idx - NWPACK;
        int j = i2 & 7, q = (i2 >> 3) & 3;
        int rest = i2 >> 5;
        int g = rest & 511, ks = (rest >> 9) % 10, s = rest / 5120;
        int kk = ks * 32 + q * 8 + j;
        float v = (kk < 300) ? w_ih[((size_t)s * 512 + g) * 300 + kk] : 0.f;
        wpre2[i2] = f2bf(v);
    }
    if (idx < 262144) {              // lxwT[s][i=256][t=128]
        int t = idx & 127, i = (idx >> 7) & 255, s = idx >> 15;
        lxwT[idx] = lxw[((size_t)(s * 128 + t)) * 256 + i];
    }
    if (idx < 65536) {               // lywT[s][i=128][t=64]
        int t = idx & 63, i = (idx >> 6) & 127, s = idx >> 13;
        lywT[idx] = lyw[((size_t)(s * 64 + t)) * 128 + i];
    }
    if (idx < 135168) {              // aw1T[i=528][j=256]
        int j = idx & 255, i = idx >> 8;
        aw1T[idx] = aw1[(size_t)j * TOT_ + i];
    }
    if (idx < 2560) {
        int c = idx % 320, s = idx / 320;
        float bv = 0.f;
        if (c < 100)      bv = b3[s*100 + c];
        else if (c < 200) bv = b4[s*100 + c - 100];
        else if (c < 300) bv = b5[s*100 + c - 200];
        bcomb[idx] = bv;
    }
}

// ---------------------------------------------------------------------------
// conv via MFMA, 2 samples per block, coalesced B direct global->VGPR with
// 2-deep register prefetch, and A-fragment (LDS) ping-pong prefetch so
// ds_read latency hides under the MFMA phase. No K-loop barriers.
// ---------------------------------------------------------------------------
__global__ __launch_bounds__(256, 2) void conv_mfma(const float* __restrict__ news,
                                                    const u16* __restrict__ wpack2,
                                                    const float* __restrict__ bcomb,
                                                    u16* __restrict__ text_bf) {
    __shared__ u16 xs[2 * 10816];
    const int tid = threadIdx.x, bid = blockIdx.x;
    const int s = bid & 7, b2d = bid >> 3, b2 = b2d / 10, d = b2d % 10;
    const int l = tid & 63, w = tid >> 6, q = l >> 4, r16 = l & 15;

    // B-frag pointers: u16 idx = s*481280 + ks*10240 + c*32 + q*8
    const u16* gp[5];
#pragma unroll
    for (int nt = 0; nt < 5; ++nt) {
        int c = w * 80 + nt * 16 + r16;
        gp[nt] = wpack2 + (size_t)s * 481280 + c * 32 + q * 8;
    }

    // prologue B prefetch (ks=0,1) issued BEFORE the staging barrier
    short8 bf0[5], bf1[5];
#pragma unroll
    for (int nt = 0; nt < 5; ++nt) bf0[nt] = *reinterpret_cast<const short8*>(gp[nt]);
#pragma unroll
    for (int nt = 0; nt < 5; ++nt) bf1[nt] = *reinterpret_cast<const short8*>(gp[nt] + 10240);

    // stage two samples f32->bf16; zero tail (rows >= 32)
#pragma unroll
    for (int sm = 0; sm < 2; ++sm) {
        const float4* xg = reinterpret_cast<const float4*>(
            news + (size_t)(((b2 * 2 + sm) * 8 + s) * 10 + d) * 9600);
        for (int i = tid; i < 2704; i += 256) {
            ushort4 u;
            if (i < 2400) {
                float4 v = xg[i];
                u.x = f2bf(v.x); u.y = f2bf(v.y); u.z = f2bf(v.z); u.w = f2bf(v.w);
            } else { u.x = 0; u.y = 0; u.z = 0; u.w = 0; }
            *reinterpret_cast<ushort4*>(&xs[sm * 10816 + 4 * i]) = u;
        }
    }
    __syncthreads();

    f32x4 acc[4][5];   // [sample*2+half][ntile]
#pragma unroll
    for (int m = 0; m < 4; ++m)
#pragma unroll
        for (int nt = 0; nt < 5; ++nt) acc[m][nt] = (f32x4)(0.f);

#define LOADA(dst, ks) do {                                                     \
    _Pragma("unroll")                                                           \
    for (int m_ = 0; m_ < 4; ++m_) {                                            \
        int off_ = (m_ >> 1) * 10816 + ((m_ & 1) * 16 + r16) * 300 + (ks) * 32 + q * 8; \
        short4v lo_ = *reinterpret_cast<const short4v*>(&xs[off_]);             \
        short4v hi_ = *reinterpret_cast<const short4v*>(&xs[off_ + 4]);         \
        dst[m_] = __builtin_shufflevector(lo_, hi_, 0, 1, 2, 3, 4, 5, 6, 7);    \
    } } while (0)

#define MFMAS(bfv, av) do {                                                     \
    __builtin_amdgcn_s_setprio(1);                                              \
    _Pragma("unroll")                                                           \
    for (int m_ = 0; m_ < 4; ++m_)                                              \
        _Pragma("unroll")                                                       \
        for (int nt_ = 0; nt_ < 5; ++nt_)                                       \
            acc[m_][nt_] = __builtin_amdgcn_mfma_f32_16x16x32_bf16(av[m_], bfv[nt_], acc[m_][nt_], 0, 0, 0); \
    __builtin_amdgcn_s_setprio(0);                                              \
    } while (0)

    short8 a0[4], a1[4];
    LOADA(a0, 0);
    for (int ks = 0; ks < 46; ks += 2) {
        LOADA(a1, ks + 1);               // prefetch A for odd phase
        MFMAS(bf0, a0);                  // consume even phase
#pragma unroll
        for (int nt = 0; nt < 5; ++nt)
            bf0[nt] = *reinterpret_cast<const short8*>(gp[nt] + (ks + 2) * 10240);

        LOADA(a0, ks + 2);               // prefetch A for next even phase
        MFMAS(bf1, a1);                  // consume odd phase
        if (ks + 3 < 47) {
#pragma unroll
            for (int nt = 0; nt < 5; ++nt)
                bf1[nt] = *reinterpret_cast<const short8*>(gp[nt] + (ks + 3) * 10240);
        }
    }
    MFMAS(bf0, a0);                      // ks = 46 tail
#undef LOADA
#undef MFMAS

    // epilogue: maxpool over valid windows, add bias, store bf16
#pragma unroll
    for (int sm = 0; sm < 2; ++sm) {
        const size_t trow = ((size_t)(s * 16 + b2 * 2 + sm) * 10 + d) * 320;
#pragma unroll
        for (int nt = 0; nt < 5; ++nt) {
            int oc = w * 80 + nt * 16 + r16;
            int L = (oc < 100) ? 30 : (oc < 200) ? 29 : 28;
            float mx = -3e38f;
#pragma unroll
            for (int r = 0; r < 4; ++r) {
                mx = fmaxf(mx, acc[sm * 2][nt][r]);          // rows 0..15 always valid
                int row1 = 16 + q * 4 + r;
                if (row1 < L) mx = fmaxf(mx, acc[sm * 2 + 1][nt][r]);
            }
            mx = fmaxf(mx, __shfl_xor(mx, 16));
            mx = fmaxf(mx, __shfl_xor(mx, 32));
            if (l < 16)
                text_bf[trow + oc] = f2bf(mx + bcomb[s * 320 + oc]);
        }
    }
}

// ---------------------------------------------------------------------------
// lstm_pre via MFMA: per (s,d): pre[16b][512g] = text[16][320] x wpre[320][512]
// A in XOR-swizzled LDS; B direct global->VGPR, coalesced via wpre2 layout.
// ---------------------------------------------------------------------------
__global__ __launch_bounds__(256) void lstm_pre_mfma(const u16* __restrict__ text_bf,
                                                     const u16* __restrict__ wpre2,
                                                     const float* __restrict__ b_ih,
                                                     const float* __restrict__ b_hh,
                                                     float* __restrict__ pre) {
    __shared__ u16 as16[16 * 320];
    const int sd = blockIdx.x, s = sd / 10, d = sd % 10;
    const int tid = threadIdx.x, l = tid & 63, w = tid >> 6, q = l >> 4, r16 = l & 15;

    // stage A (16 rows x 640B), XOR-swizzle 16B chunks: chunk' = chunk ^ (row&7)
    for (int i = tid; i < 640; i += 256) {
        int r = i / 40, c = i % 40;
        *reinterpret_cast<float4*>(as16 + r * 320 + ((c ^ (r & 7)) << 3)) =
            *reinterpret_cast<const float4*>(text_bf + ((size_t)(s * 16 + r) * 10 + d) * 320 + c * 8);
    }
    __syncthreads();

    // u16 idx = s*163840 + ks*16384 + g*32 + q*8
    const u16* gpb[8];
#pragma unroll
    for (int nt = 0; nt < 8; ++nt) {
        int g = w * 128 + nt * 16 + r16;
        gpb[nt] = wpre2 + (size_t)s * 163840 + g * 32 + q * 8;
    }

    f32x4 acc[8];
#pragma unroll
    for (int nt = 0; nt < 8; ++nt) acc[nt] = (f32x4)(0.f);

    for (int ks = 0; ks < 10; ++ks) {
        short8 a = *reinterpret_cast<const short8*>(
            as16 + r16 * 320 + (((ks * 4 + q) ^ (r16 & 7)) << 3));
#pragma unroll
        for (int nt = 0; nt < 8; ++nt) {
            short8 bf = *reinterpret_cast<const short8*>(gpb[nt] + ks * 16384);
            acc[nt] = __builtin_amdgcn_mfma_f32_16x16x32_bf16(a, bf, acc[nt], 0, 0, 0);
        }
    }

#pragma unroll
    for (int nt = 0; nt < 8; ++nt) {
        int g = w * 128 + nt * 16 + r16;
        float bias = b_ih[s * 512 + g] + b_hh[s * 512 + g];
#pragma unroll
        for (int r = 0; r < 4; ++r) {
            int brow = q * 4 + r;
            pre[((size_t)sd * 16 + brow) * 512 + g] = acc[nt][r] + bias;
        }
    }
}

// ---------------------------------------------------------------------------
// lstm_tail: sequential LSTM + degenerate attention + linX + linY (fused).
// w_hh rows register-cached via coalesced LDS chunk staging (4 x 128 rows,
// [128][129] pad -> conflict-free). linX/linY use transposed (coalesced) W.
// ---------------------------------------------------------------------------
__global__ __launch_bounds__(512) void lstm_tail(const float* __restrict__ pre,
                                                 const float* __restrict__ w_hh,
                                                 const float* __restrict__ lxwT, const float* __restrict__ lxb,
                                                 const float* __restrict__ lywT, const float* __restrict__ lyb,
                                                 float* __restrict__ total) {
    __shared__ float wchunk[128][129];
    __shared__ float h_lds[H_];
    __shared__ float gates[G4_];
    __shared__ float comb_l[256];
    __shared__ __align__(16) float hx[H_];
    const int sb = blockIdx.x;
    const int s = sb / B_, b = sb % B_;
    const int t = threadIdx.x;

    // stage w_hh[s] rows into per-thread regs, coalesced via LDS
    float wrs[128];
    for (int c = 0; c < 4; ++c) {
        for (int i2 = t; i2 < 128 * 32; i2 += 512) {
            int row = i2 >> 5, fq = i2 & 31;
            float4 v = *reinterpret_cast<const float4*>(
                w_hh + ((size_t)(s * G4_ + c * 128 + row)) * H_ + fq * 4);
            wchunk[row][fq * 4 + 0] = v.x; wchunk[row][fq * 4 + 1] = v.y;
            wchunk[row][fq * 4 + 2] = v.z; wchunk[row][fq * 4 + 3] = v.w;
        }
        __syncthreads();
        if ((t >> 7) == c) {
            int r = t & 127;
#pragma unroll
            for (int i = 0; i < 128; ++i) wrs[i] = wchunk[r][i];
        }
        __syncthreads();
    }

    float cc = 0.f, hsum = 0.f, hval = 0.f;
    if (t < H_) h_lds[t] = 0.f;
    __syncthreads();

    for (int d = 0; d < D_; ++d) {
        float a0 = pre[(((size_t)(s * D_ + d) * B_ + b)) * G4_ + t];
        float a1 = 0.f, a2 = 0.f, a3 = 0.f;
#pragma unroll
        for (int i = 0; i < 128; i += 4) {
            float4 h4 = *reinterpret_cast<const float4*>(&h_lds[i]);
            a0 = fmaf(wrs[i + 0], h4.x, a0);
            a1 = fmaf(wrs[i + 1], h4.y, a1);
            a2 = fmaf(wrs[i + 2], h4.z, a2);
            a3 = fmaf(wrs[i + 3], h4.w, a3);
        }
        gates[t] = (a0 + a1) + (a2 + a3);
        __syncthreads();
        if (t < H_) {
            float ig = 1.f / (1.f + expf(-gates[t]));
            float fg = 1.f / (1.f + expf(-gates[H_ + t]));
            float gg = tanhf(gates[2 * H_ + t]);
            float og = 1.f / (1.f + expf(-gates[3 * H_ + t]));
            cc = fg * cc + ig * gg;
            hval = og * tanhf(cc);
            hsum += hval;
            h_lds[t] = hval;
        }
        __syncthreads();
    }
    if (t < H_) { comb_l[t] = hval; comb_l[H_ + t] = hsum; }
    __syncthreads();
    if (t < H_) {                       // linX: coalesced lxwT[s][i][t]
        const float* wv = lxwT + (size_t)s * 256 * 128 + t;
        float a0 = lxb[s * H_ + t], a1 = 0.f;
        for (int i = 0; i < 256; i += 2) {
            a0 = fmaf(comb_l[i], wv[(size_t)i * 128], a0);
            a1 = fmaf(comb_l[i + 1], wv[(size_t)(i + 1) * 128], a1);
        }
        hx[t] = fmaxf(a0 + a1, 0.f);
    }
    __syncthreads();
    if (t < 64) {                       // linY: coalesced lywT[s][i][t]
        const float* wv = lywT + (size_t)s * 128 * 64 + t;
        float a0 = lyb[s * 64 + t], a1 = 0.f;
        for (int i = 0; i < 128; i += 2) {
            a0 = fmaf(hx[i], wv[(size_t)i * 64], a0);
            a1 = fmaf(hx[i + 1], wv[(size_t)(i + 1) * 64], a1);
        }
        total[(size_t)b * 512 + s * 64 + t] = fmaxf(a0 + a1, 0.f);
    }
}

// ---------------------------------------------------------------------------
// head_feats: feats MLP + arch head fused; aw1T coalesced. Block per batch b.
// ---------------------------------------------------------------------------
__global__ __launch_bounds__(256) void head_feats(const float* __restrict__ total,
                                                  const float* __restrict__ sf,
                                                  const float* __restrict__ w1, const float* __restrict__ b1,
                                                  const float* __restrict__ w2, const float* __restrict__ b2,
                                                  const float* __restrict__ aw1T, const float* __restrict__ ab1,
                                                  const float* __restrict__ aw2, const float* __restrict__ ab2,
                                                  const float* __restrict__ avar,
                                                  float* __restrict__ out) {
    __shared__ __align__(16) float tr[TOT_];
    __shared__ float hid[MID_];
    __shared__ float h1f[24];
    const int bb = blockIdx.x, t = threadIdx.x;
    if (t < 128)
        reinterpret_cast<float4*>(tr)[t] = reinterpret_cast<const float4*>(total + (size_t)bb * 512)[t];
    if (t < 24) {
        float acc = b1[t];
        for (int i = 0; i < SDIM_; ++i) acc = fmaf(sf[bb * SDIM_ + i], w1[t * SDIM_ + i], acc);
        h1f[t] = fmaxf(acc, 0.f);
    }
    __syncthreads();
    if (t < 16) {
        float acc = b2[t];
        for (int i = 0; i < 24; ++i) acc = fmaf(h1f[i], w2[t * 24 + i], acc);
        tr[512 + t] = acc;
    }
    __syncthreads();
    {   // layer1: hid[t] = relu(ab1[t] + sum_i tr[i]*aw1T[i][t]) -- coalesced
        const float* wv = aw1T + t;
        float a0 = ab1[t], a1 = 0.f, a2 = 0.f, a3 = 0.f;
        for (int i = 0; i < TOT_; i += 4) {
            a0 = fmaf(tr[i + 0], wv[(size_t)(i + 0) * 256], a0);
            a1 = fmaf(tr[i + 1], wv[(size_t)(i + 1) * 256], a1);
            a2 = fmaf(tr[i + 2], wv[(size_t)(i + 2) * 256], a2);
            a3 = fmaf(tr[i + 3], wv[(size_t)(i + 3) * 256], a3);
        }
        hid[t] = fmaxf((a0 + a1) + (a2 + a3), 0.f);
    }
    __syncthreads();
    if (t < 8) {
        float acc = ab2[t];
        const float* wv = aw2 + (size_t)t * MID_;
        for (int i = 0; i < MID_; ++i) acc = fmaf(hid[i], wv[i], acc);
        out[bb * 8 + t] = tanhf(acc);
    }
    if (bb == 0 && t >= 8 && t < 16) out[128 + (t - 8)] = expf(avar[t - 8]);
}

// ---------------------------------------------------------------------------
extern "C" void kernel_launch(void* const* d_in, const int* in_sizes, int n_in,
                              void* d_out, int out_size, void* d_ws, size_t ws_size,
                              hipStream_t stream) {
    const float* news = (const float*)d_in[0];
    const float* sf   = (const float*)d_in[1];
    const float* w3   = (const float*)d_in[2];  const float* b3 = (const float*)d_in[3];
    const float* w4   = (const float*)d_in[4];  const float* b4 = (const float*)d_in[5];
    const float* w5   = (const float*)d_in[6];  const float* b5 = (const float*)d_in[7];
    const float* w_ih = (const float*)d_in[8];  const float* w_hh = (const float*)d_in[9];
    const float* b_ih = (const float*)d_in[10]; const float* b_hh = (const float*)d_in[11];
    const float* lxw  = (const float*)d_in[12]; const float* lxb = (const float*)d_in[13];
    const float* lyw  = (const float*)d_in[14]; const float* lyb = (const float*)d_in[15];
    const float* w1   = (const float*)d_in[16]; const float* b1 = (const float*)d_in[17];
    const float* w2   = (const float*)d_in[18]; const float* b2 = (const float*)d_in[19];
    const float* aw1  = (const float*)d_in[20]; const float* ab1 = (const float*)d_in[21];
    const float* aw2  = (const float*)d_in[22]; const float* ab2 = (const float*)d_in[23];
    const float* avar = (const float*)d_in[24];

    char* ws = (char*)d_ws;
    u16*   wpack2  = (u16*)ws;                                  // 7,700,480 B
    u16*   wpre2   = (u16*)(ws + 7700480);                      // 2,621,440 B
    float* bcomb   = (float*)(ws + 10321920);                   // 10,240 B
    u16*   text_bf = (u16*)(ws + 10332160);                     // 819,200 B
    float* pre     = (float*)(ws + 11151360);                   // 2,621,440 B
    float* total   = (float*)(ws + 13772800);                   // 32,768 B
    float* lxwT    = (float*)(ws + 13805568);                   // 1,048,576 B
    float* lywT    = (float*)(ws + 14854144);                   // 262,144 B
    float* aw1T    = (float*)(ws + 15116288);                   // 540,672 B (end ~15.7 MB)

    prep<<<(NWPACK + NWPRE + 255) / 256, 256, 0, stream>>>(w3, b3, w4, b4, w5, b5, w_ih,
                                                           lxw, lyw, aw1,
                                                           wpack2, wpre2, bcomb, lxwT, lywT, aw1T);
    conv_mfma<<<640, 256, 0, stream>>>(news, wpack2, bcomb, text_bf);
    lstm_pre_mfma<<<S_ * D_, 256, 0, stream>>>(text_bf, wpre2, b_ih, b_hh, pre);
    lstm_tail<<<S_ * B_, 512, 0, stream>>>(pre, w_hh, lxwT, lxb, lywT, lyb, total);
    head_feats<<<B_, 256, 0, stream>>>(total, sf, w1, b1, w2, b2, aw1T, ab1, aw2, ab2, avar, (float*)d_out);
}